// Round 4
// baseline (83.214 us; speedup 1.0000x reference)
//
#include <hip/hip_runtime.h>

// B=64, D=2048, UNITS=1024, NW=64; L = in_sizes[3]/(UNITS*NW) (~56).
//
// out[b,u] = sum_i x[b,i] * W[u,i] + bias[u], W[u,i] = w[k] where bucket k of
// unit u contains position i (indices 1-shifted, 0 = pad).
//
// KEY INVARIANT (from reference _build_hash_indices): the 64 buckets of unit
// u PARTITION all 2048 positions — every rows[uu][i] is written EXACTLY once
// by the scatter. Therefore the LDS zero-init phase is dead work: removed,
// along with its barrier. w[k] is wave-uniform -> scalar load (no w_lds).
//
// R13 changes vs R12 (theory: if kernel ~30us it's the shared serial phase
// structure, since 2x volume changes in both directions were time-neutral):
//   1. Phase 0 (zeroing + w_lds + barrier) DELETED — partition coverage.
//   2. ONE barrier total (after scatter, before compute).
//   3. Phase 2 software-pipelined: prefetch step t+1's x float4s before
//      consuming step t's (breaks the per-step vmem latency gate).
// Prediction: World K (kernel latency-structured) -> dur ~73-77;
// World F (harness floor) -> unchanged ~80 -> declare floor next round.
//
// Journal: R9 U=8/BS=2 80.1; R11 two-kernel split 92.8 (REGRESSED: 16K
// tiny-block dispatch + launch gap); R12 U=4/BS=1 80.7 (phase-1 halving
// neutral). Timed region carries ~43us ws-poison fill (268MB @ 6.1-6.5 TB/s
// = the achievable HBM ceiling) + ~60-dispatch reset train.

#define B_DIM   64
#define D_DIM   2048
#define D4      (D_DIM / 4)     // 512 float4 per row
#define UNITS_N 1024
#define NW_N    64
#define U_PER_BLOCK 4
#define B_PER_BLOCK B_DIM                           // 64
#define THREADS 1024
#define WAVES   (THREADS / 64)                      // 16
#define PAIRS_PER_WAVE (U_PER_BLOCK * NW_N / WAVES) // 16
#define ROWS_PER_WAVE  (B_PER_BLOCK / WAVES)        // 4
#define STEPS   (D4 / 64)                           // 8

__global__ __launch_bounds__(THREADS)   // NO 2nd arg: 64-VGPR cap + spill (R5)
void EfficientHashedLinear_72043781423546_kernel(
    const float* __restrict__ x,        // (64, 2048)
    const float* __restrict__ w,        // (64,)
    const float* __restrict__ bias,     // (1024,)
    const int*   __restrict__ indices,  // (UNITS, NW, L) int32
    float*       __restrict__ out,      // (64, 1024)
    int L)
{
    __shared__ float rows[U_PER_BLOCK][D_DIM];   // 16 KB, NOT zero-initialized

    const int tid  = threadIdx.x;
    const int wave = tid >> 6;          // 0..15
    const int lane = tid & 63;
    const int u0   = blockIdx.x * U_PER_BLOCK;

    // Phase 1a: index gather — 16 independent lane-predicated loads/wave,
    // all issued up front (one batched HBM round trip, nothing precedes it).
    int idxv[PAIRS_PER_WAVE];
    #pragma unroll
    for (int p = 0; p < PAIRS_PER_WAVE; ++p) {
        const int pair = wave * PAIRS_PER_WAVE + p;   // 0..255
        const int uu   = pair >> 6;                   // 0..3
        const int k    = pair & 63;                   // 0..63
        const int* bp  = indices + ((size_t)(u0 + uu) * NW_N + k) * L;
        idxv[p] = (lane < L) ? bp[lane] : 0;
    }

    // Phase 1b: scatter (LDS only). Buckets partition positions -> each
    // rows[uu][i] written exactly once across the whole block; no races,
    // no zero-init, no pre-barrier needed. w[k] wave-uniform -> s_load.
    #pragma unroll
    for (int p = 0; p < PAIRS_PER_WAVE; ++p) {
        const int pair = wave * PAIRS_PER_WAVE + p;
        const int uu   = pair >> 6;
        const int k    = pair & 63;
        const float wk = w[k];
        if (idxv[p] > 0) rows[uu][idxv[p] - 1] = wk;
    }
    // Generic tail for L > 64 (not expected with this data; kept for safety).
    if (L > 64) {
        #pragma unroll 1
        for (int p = 0; p < PAIRS_PER_WAVE; ++p) {
            const int pair = wave * PAIRS_PER_WAVE + p;
            const int uu   = pair >> 6;
            const int k    = pair & 63;
            const int* bp  = indices + ((size_t)(u0 + uu) * NW_N + k) * L;
            const float wk = w[k];
            for (int l = 64 + lane; l < L; l += 64) {
                int idx = bp[l];
                if (idx > 0) rows[uu][idx - 1] = wk;
            }
        }
    }
    __syncthreads();   // the ONLY barrier: scatter complete before reads

    // Phase 2: wave owns 4 batch rows x 4 units. Software-pipelined:
    // prefetch step t+1's x float4s before consuming step t's.
    const int b0 = wave * ROWS_PER_WAVE;
    const float4* x4 = (const float4*)x;

    float acc[ROWS_PER_WAVE][U_PER_BLOCK];
    #pragma unroll
    for (int bj = 0; bj < ROWS_PER_WAVE; ++bj)
        #pragma unroll
        for (int uu = 0; uu < U_PER_BLOCK; ++uu)
            acc[bj][uu] = 0.0f;

    float4 xv[ROWS_PER_WAVE];
    #pragma unroll
    for (int bj = 0; bj < ROWS_PER_WAVE; ++bj)
        xv[bj] = x4[(b0 + bj) * D4 + lane];           // prologue: step 0

    #pragma unroll 1   // pipelined; live set ~110 VGPR, no spill
    for (int step = 0; step < STEPS; ++step) {
        const int i4 = step * 64 + lane;              // 0..511
        float4 xn[ROWS_PER_WAVE];
        if (step + 1 < STEPS) {
            const int n4 = i4 + 64;
            #pragma unroll
            for (int bj = 0; bj < ROWS_PER_WAVE; ++bj)
                xn[bj] = x4[(b0 + bj) * D4 + n4];     // prefetch t+1
        }
        #pragma unroll
        for (int uu = 0; uu < U_PER_BLOCK; ++uu) {
            const float4 rv = ((const float4*)rows[uu])[i4];   // ds_read_b128
            #pragma unroll
            for (int bj = 0; bj < ROWS_PER_WAVE; ++bj) {
                acc[bj][uu] += xv[bj].x * rv.x;
                acc[bj][uu] += xv[bj].y * rv.y;
                acc[bj][uu] += xv[bj].z * rv.z;
                acc[bj][uu] += xv[bj].w * rv.w;
            }
        }
        #pragma unroll
        for (int bj = 0; bj < ROWS_PER_WAVE; ++bj)
            xv[bj] = xn[bj];
    }

    // Phase 3: butterfly reduce, add bias, store (16 outputs/wave).
    #pragma unroll
    for (int bj = 0; bj < ROWS_PER_WAVE; ++bj) {
        #pragma unroll
        for (int uu = 0; uu < U_PER_BLOCK; ++uu) {
            float v = acc[bj][uu];
            #pragma unroll
            for (int off = 32; off > 0; off >>= 1)
                v += __shfl_down(v, off, 64);
            if (lane == 0)
                out[(b0 + bj) * UNITS_N + (u0 + uu)] = v + bias[u0 + uu];
        }
    }
}

extern "C" void kernel_launch(void* const* d_in, const int* in_sizes, int n_in,
                              void* d_out, int out_size, void* d_ws, size_t ws_size,
                              hipStream_t stream) {
    const float* x       = (const float*)d_in[0];
    const float* w       = (const float*)d_in[1];
    const float* bias    = (const float*)d_in[2];
    const int*   indices = (const int*)d_in[3];
    float*       out     = (float*)d_out;

    const int L = in_sizes[3] / (UNITS_N * NW_N);

    dim3 grid(UNITS_N / U_PER_BLOCK);   // 256 blocks = 1/CU
    dim3 block(THREADS);                // 1024 threads = 16 waves
    EfficientHashedLinear_72043781423546_kernel<<<grid, block, 0, stream>>>(
        x, w, bias, indices, out, L);
}